// Round 1
// baseline (33280.768 us; speedup 1.0000x reference)
//
#include <hip/hip_runtime.h>
#include <hip/hip_bf16.h>
#include <stdint.h>

// LSTM: B=64, T=512, IN=512, H=1024, K=IN+H=1536, gates=4096.
// One persistent cooperative kernel, 64 WGs x 512 threads (8 waves).
// Per step: gates = [x_t | h_t] @ W_i2h via bf16 hi/lo split (3 MFMA products,
// ~1e-5 rel err), cell update in registers, h broadcast via agent-scope (L3)
// atomics, hand-rolled relaxed grid barrier (no L2-invalidating acquire).

typedef __bf16 bf16x8 __attribute__((ext_vector_type(8)));
typedef __bf16 bf16x4 __attribute__((ext_vector_type(4)));
typedef float  f32x4  __attribute__((ext_vector_type(4)));

#define NWG   64
#define NTHR  512

// workspace layout (bytes)
#define WS_CTR    0
#define WS_HBUF   1024
#define HB_STRIDE 262144        // per h buffer: hi 128KB + lo 128KB
#define HB_LO     131072
#define WS_HLAST  (WS_HBUF + 2*HB_STRIDE)      // 64x1024 f32 = 256KB
#define WS_WHI    (WS_HLAST + 262144)
#define W_BYTES   (256*192*16*8*2)             // 12.58MB (frag layout, bf16)
#define WS_WLO    (WS_WHI + W_BYTES)

// LDS layout: buf0 @0 (hi 32KB, lo 32KB), buf1 @65536, exch @131072 (8KB)
#define LDS_BYTES 139264

__device__ __forceinline__ float sigm(float x) {
    return __builtin_amdgcn_rcpf(1.0f + __expf(-x));
}
__device__ __forceinline__ float tanh_f(float x) {
    x = fminf(fmaxf(x, -20.0f), 20.0f);
    float e = __expf(-2.0f * x);
    return (1.0f - e) * __builtin_amdgcn_rcpf(1.0f + e);
}

__device__ __forceinline__ void issue_x(float4* xr, const float* __restrict__ x,
                                        int t, int c, int tid) {
    int b = tid >> 3, jj = tid & 7;
    const float* base = x + ((size_t)b * 512 + t) * 512 + c * 256 + jj * 4;
#pragma unroll
    for (int j = 0; j < 8; ++j) xr[j] = *(const float4*)(base + j * 32);
}

__device__ __forceinline__ void commit_x(const float4* xr, char* buf, int tid) {
    int b = tid >> 3, jj = tid & 7;
#pragma unroll
    for (int j = 0; j < 8; ++j) {
        int kl = jj * 4 + j * 32;
        int lkb = kl >> 3, sub = kl & 7;                  // sub in {0,4}
        uint32_t ad = (uint32_t)((lkb << 6) + (b ^ (lkb & 7))) * 16 + sub * 2;
        float4 v = xr[j];
        bf16x4 hi = {(__bf16)v.x, (__bf16)v.y, (__bf16)v.z, (__bf16)v.w};
        bf16x4 lo = {(__bf16)(v.x - (float)hi[0]), (__bf16)(v.y - (float)hi[1]),
                     (__bf16)(v.z - (float)hi[2]), (__bf16)(v.w - (float)hi[3])};
        *(bf16x4*)(buf + ad) = hi;
        *(bf16x4*)(buf + 32768 + ad) = lo;
    }
}

__device__ __forceinline__ void issue_h(unsigned long long* ha,
                                        const char* hb_rd, int c, int tid) {
    const char* shi = hb_rd + (c - 2) * 32768;
#pragma unroll
    for (int i = 0; i < 4; ++i) {
        uint32_t o = (uint32_t)tid * 16 + i * 8192;
        ha[2*i]     = __hip_atomic_load((const unsigned long long*)(shi + o),
                        __ATOMIC_RELAXED, __HIP_MEMORY_SCOPE_AGENT);
        ha[2*i + 1] = __hip_atomic_load((const unsigned long long*)(shi + o + 8),
                        __ATOMIC_RELAXED, __HIP_MEMORY_SCOPE_AGENT);
        ha[8 + 2*i]     = __hip_atomic_load((const unsigned long long*)(shi + HB_LO + o),
                        __ATOMIC_RELAXED, __HIP_MEMORY_SCOPE_AGENT);
        ha[8 + 2*i + 1] = __hip_atomic_load((const unsigned long long*)(shi + HB_LO + o + 8),
                        __ATOMIC_RELAXED, __HIP_MEMORY_SCOPE_AGENT);
    }
}

__device__ __forceinline__ void commit_h(const unsigned long long* ha, char* buf, int tid) {
#pragma unroll
    for (int i = 0; i < 4; ++i) {
        uint32_t o = (uint32_t)tid * 16 + i * 8192;
        *(unsigned long long*)(buf + o)             = ha[2*i];
        *(unsigned long long*)(buf + o + 8)         = ha[2*i + 1];
        *(unsigned long long*)(buf + 32768 + o)     = ha[8 + 2*i];
        *(unsigned long long*)(buf + 32768 + o + 8) = ha[8 + 2*i + 1];
    }
}

__device__ __forceinline__ void compute_chunk(const char* cbuf, int c, int lane, int mt,
        const char* __restrict__ WhiB, const char* __restrict__ WloB,
        uint32_t wb0, uint32_t wb1, f32x4& acc0, f32x4& acc1) {
    const int g = lane >> 4, nl = lane & 15;
    const int r = mt * 16 + nl;
#pragma unroll
    for (int ks = 0; ks < 8; ++ks) {
        int lkblk = 4 * ks + g;
        uint32_t aoff = (uint32_t)((lkblk << 6) + (r ^ (lkblk & 7))) << 4;
        bf16x8 ahi = *(const bf16x8*)(cbuf + aoff);
        bf16x8 alo = *(const bf16x8*)(cbuf + aoff + 32768);
        uint32_t ko = (uint32_t)(c * 32 + 4 * ks) << 8;   // kblk*256B
        bf16x8 b0h = *(const bf16x8*)(WhiB + wb0 + ko);
        bf16x8 b0l = *(const bf16x8*)(WloB + wb0 + ko);
        bf16x8 b1h = *(const bf16x8*)(WhiB + wb1 + ko);
        bf16x8 b1l = *(const bf16x8*)(WloB + wb1 + ko);
        acc0 = __builtin_amdgcn_mfma_f32_16x16x32_bf16(ahi, b0h, acc0, 0, 0, 0);
        acc1 = __builtin_amdgcn_mfma_f32_16x16x32_bf16(ahi, b1h, acc1, 0, 0, 0);
        acc0 = __builtin_amdgcn_mfma_f32_16x16x32_bf16(ahi, b0l, acc0, 0, 0, 0);
        acc1 = __builtin_amdgcn_mfma_f32_16x16x32_bf16(ahi, b1l, acc1, 0, 0, 0);
        acc0 = __builtin_amdgcn_mfma_f32_16x16x32_bf16(alo, b0h, acc0, 0, 0, 0);
        acc1 = __builtin_amdgcn_mfma_f32_16x16x32_bf16(alo, b1h, acc1, 0, 0, 0);
    }
}

__global__ void lstm_init(char* ws) {
    int id = blockIdx.x * 256 + threadIdx.x;
    float4 z = {0.f, 0.f, 0.f, 0.f};
    ((float4*)(ws + WS_HBUF))[id] = z;      // zero h_buf[0] hi+lo (256KB)
    if (id == 0) *(unsigned*)(ws + WS_CTR) = 0u;
}

__global__ __launch_bounds__(NTHR) void lstm_main(
        const float* __restrict__ x, const float* __restrict__ Wi2h,
        const float* __restrict__ bi2h, const float* __restrict__ Wh2o,
        const float* __restrict__ bh2o, float* __restrict__ out,
        char* __restrict__ ws) {
    extern __shared__ char lds[];
    const int tid = threadIdx.x;
    const int wg = blockIdx.x;
    const int w = tid >> 6, lane = tid & 63, g = lane >> 4, nl = lane & 15;
    const int mt = w & 3, ntp = w >> 2;
    const int ntg0 = (ntp * 2) * 64 + wg, ntg1 = (ntp * 2 + 1) * 64 + wg;

    __bf16* Whi = (__bf16*)(ws + WS_WHI);
    __bf16* Wlo = (__bf16*)(ws + WS_WLO);

    // ---- phase 0: convert this WG's W slice to hi/lo bf16 fragments ----
    {
        int nlo = tid & 15, kgrp = tid >> 4;   // 16 x 32
        for (int nt = 0; nt < 4; ++nt) {
            int ntg = nt * 64 + wg;
            int n = ntg * 16 + nlo;
            for (int kb = 0; kb < 6; ++kb) {
                int kblk = kgrp * 6 + kb;      // 0..191
                bf16x8 hi8, lo8;
#pragma unroll
                for (int j = 0; j < 8; ++j) {
                    float v = Wi2h[(size_t)(kblk * 8 + j) * 4096 + n];
                    __bf16 h = (__bf16)v;
                    hi8[j] = h;
                    lo8[j] = (__bf16)(v - (float)h);
                }
                size_t fo = ((size_t)(ntg * 192 + kblk) * 16 + nlo) * 8;
                *(bf16x8*)(Whi + fo) = hi8;
                *(bf16x8*)(Wlo + fo) = lo8;
            }
        }
    }
    float bias0 = bi2h[ntg0 * 16 + nl];
    float bias1 = bi2h[ntg1 * 16 + nl];
    __syncthreads();

    const uint32_t lane_off = ((uint32_t)g << 8) + ((uint32_t)nl << 4);
    const uint32_t wb0 = (uint32_t)ntg0 * 49152 + lane_off;
    const uint32_t wb1 = (uint32_t)ntg1 * 49152 + lane_off;
    unsigned* ctr = (unsigned*)(ws + WS_CTR);
    float creg[4] = {0.f, 0.f, 0.f, 0.f};

    float4 xp[8];
    issue_x(xp, x, 0, 0, tid);     // prefetch x chunk0 of step 0

#pragma unroll 1
    for (int t = 0; t < 512; ++t) {
        char* hb_rd = ws + WS_HBUF + (size_t)(t & 1) * HB_STRIDE;
        char* hb_wr = ws + WS_HBUF + (size_t)((t + 1) & 1) * HB_STRIDE;
        f32x4 acc0 = {0.f, 0.f, 0.f, 0.f}, acc1 = {0.f, 0.f, 0.f, 0.f};

        commit_x(xp, lds, tid);            // chunk0 -> buf0
        __syncthreads();
#pragma unroll
        for (int c = 0; c < 6; ++c) {
            char* cbuf = lds + (c & 1) * 65536;
            char* nbuf = lds + ((c + 1) & 1) * 65536;
            float4 xr[8];
            unsigned long long ha[16];
            if (c < 5) {
                if (c + 1 < 2) issue_x(xr, x, t, c + 1, tid);
                else           issue_h(ha, hb_rd, c + 1, tid);
            }
            compute_chunk(cbuf, c, lane, mt, (const char*)Whi, (const char*)Wlo,
                          wb0, wb1, acc0, acc1);
            if (c < 5) {
                if (c + 1 < 2) commit_x(xr, nbuf, tid);
                else           commit_h(ha, nbuf, tid);
                __syncthreads();
            }
        }

        // ---- epilogue: exchange g,o preacts; cell update on waves 0-3 ----
        float* exch = (float*)(lds + 131072);
        if (ntp == 1) {
#pragma unroll
            for (int j = 0; j < 4; ++j) {
                exch[(mt * 2 + 0) * 256 + (4 * g + j) * 16 + nl] = acc0[j] + bias0;
                exch[(mt * 2 + 1) * 256 + (4 * g + j) * 16 + nl] = acc1[j] + bias1;
            }
        }
        __syncthreads();
        if (ntp == 0) {
#pragma unroll
            for (int j = 0; j < 4; ++j) {
                float ipre = acc0[j] + bias0;
                float fpre = acc1[j] + bias1;
                float gpre = exch[(mt * 2 + 0) * 256 + (4 * g + j) * 16 + nl];
                float opre = exch[(mt * 2 + 1) * 256 + (4 * g + j) * 16 + nl];
                float iv = sigm(ipre), fv = sigm(fpre);
                float gv = tanh_f(gpre), ov = sigm(opre);
                float cc = fv * creg[j] + iv * gv;
                creg[j] = cc;
                float hv = ov * tanh_f(cc);
                __bf16 hh = (__bf16)hv;
                __bf16 hl = (__bf16)(hv - (float)hh);
                int hc = (wg << 4) + nl;
                int bb = mt * 16 + 4 * g + j;
                int lkb = (hc >> 3) & 31, ch = hc >> 8, sub = hc & 7;
                uint32_t off = ((uint32_t)(ch * 32 + lkb) * 64 + (uint32_t)(bb ^ (lkb & 7))) * 8 + sub;
                __hip_atomic_store((unsigned short*)hb_wr + off,
                                   __builtin_bit_cast(unsigned short, hh),
                                   __ATOMIC_RELAXED, __HIP_MEMORY_SCOPE_AGENT);
                __hip_atomic_store((unsigned short*)(hb_wr + HB_LO) + off,
                                   __builtin_bit_cast(unsigned short, hl),
                                   __ATOMIC_RELAXED, __HIP_MEMORY_SCOPE_AGENT);
                if (t == 511)
                    __hip_atomic_store((float*)(ws + WS_HLAST) + bb * 1024 + hc, hv,
                                       __ATOMIC_RELAXED, __HIP_MEMORY_SCOPE_AGENT);
            }
        }

        __syncthreads();                 // drains each wave's vmcnt (stores at L3)
        if (t < 511) issue_x(xp, x, t + 1, 0, tid);   // prefetch under barrier
        if (tid == 0) {
            __hip_atomic_fetch_add(ctr, 1u, __ATOMIC_RELAXED, __HIP_MEMORY_SCOPE_AGENT);
            unsigned tgt = (unsigned)(t + 1) * 64u;
            while (__hip_atomic_load(ctr, __ATOMIC_RELAXED, __HIP_MEMORY_SCOPE_AGENT) < tgt)
                __builtin_amdgcn_s_sleep(1);
        }
        __syncthreads();
        asm volatile("" ::: "memory");
    }

    // ---- final projection: out = h_last @ W_h2o + b_h2o ----
    int id = wg * NTHR + tid;            // 0..32767
    int nn = id & 511, bb2 = id >> 9;
    const float* hrow = (const float*)(ws + WS_HLAST) + bb2 * 1024;
    const float* wc = Wh2o + nn;
    float acc = bh2o[nn];
#pragma unroll 1
    for (int k = 0; k < 1024; k += 4) {
        acc += hrow[k]     * wc[(size_t)k * 512];
        acc += hrow[k + 1] * wc[(size_t)(k + 1) * 512];
        acc += hrow[k + 2] * wc[(size_t)(k + 2) * 512];
        acc += hrow[k + 3] * wc[(size_t)(k + 3) * 512];
    }
    out[bb2 * 512 + nn] = acc;
}

extern "C" void kernel_launch(void* const* d_in, const int* in_sizes, int n_in,
                              void* d_out, int out_size, void* d_ws, size_t ws_size,
                              hipStream_t stream) {
    const float* x    = (const float*)d_in[0];
    const float* Wi2h = (const float*)d_in[1];
    const float* bi2h = (const float*)d_in[2];
    const float* Wh2o = (const float*)d_in[3];
    const float* bh2o = (const float*)d_in[4];
    float* out = (float*)d_out;
    char* ws = (char*)d_ws;

    hipFuncSetAttribute(reinterpret_cast<const void*>(lstm_main),
                        hipFuncAttributeMaxDynamicSharedMemorySize, LDS_BYTES);

    lstm_init<<<64, 256, 0, stream>>>(ws);

    void* args[] = {(void*)&x, (void*)&Wi2h, (void*)&bi2h, (void*)&Wh2o,
                    (void*)&bh2o, (void*)&out, (void*)&ws};
    hipLaunchCooperativeKernel(reinterpret_cast<void*>(lstm_main),
                               dim3(NWG), dim3(NTHR), args, LDS_BYTES, stream);
}

// Round 4
// 12919.070 us; speedup vs baseline: 2.5761x; 2.5761x over previous
//
#include <hip/hip_runtime.h>
#include <hip/hip_bf16.h>
#include <stdint.h>

// LSTM B=64, T=512, IN=512, H=1024, K=1536, gates=4096.
// 256 WGs x 512 thr, cooperative. W (hi/lo bf16 frags) resident in LDS
// (96 KB/WG, built in phase 0) -> zero per-step W memory traffic.
// Per step: A = [x_t | h_t] broadcast via L2 (plain loads after acquire-fence);
// h written as agent-scope write-through stores (never dirty in L2).
// Grid sync: per-WG monotonic flags + wg0 aggregator -> "go" word.

typedef __bf16 bf16x8 __attribute__((ext_vector_type(8)));
typedef float  f32x4  __attribute__((ext_vector_type(4)));

#define NWG   256
#define NTHR  512

// workspace layout (bytes)
#define WS_FLAGS  0            // 256 * 4B monotonic step counters
#define WS_GO     2048         // 4B
#define WS_HBUF   4096         // 2 parities * 256 KB
#define HB_STRIDE 262144       // per parity: hi 128 KB + lo 128 KB
#define HB_LO     131072
#define WS_HLAST  (WS_HBUF + 2*HB_STRIDE)   // 64x1024 f32 = 256 KB

// LDS layout (dynamic)
#define L_WHI   0              // 192 akblk * 16 col * 8 bf16 = 48 KB
#define L_WLO   49152          // 48 KB
#define L_EXCH  98304          // 4 KB f32
#define L_EXCH2 102400         // 4 KB f32
#define LDS_BYTES 106496

__device__ __forceinline__ float sigm(float x) {
    return __builtin_amdgcn_rcpf(1.0f + __expf(-x));
}
__device__ __forceinline__ float tanh_f(float x) {
    x = fminf(fmaxf(x, -20.0f), 20.0f);
    float e = __expf(-2.0f * x);
    return (1.0f - e) * __builtin_amdgcn_rcpf(1.0f + e);
}

__global__ void lstm_init(char* __restrict__ ws) {
    // zero flags, go, and h-buffer parity 0 (266240 bytes = 66560 dwords)
    int id = blockIdx.x * 256 + threadIdx.x;
    for (int i = id; i < 66560; i += 256 * 256)
        __hip_atomic_store((unsigned*)ws + i, 0u,
                           __ATOMIC_RELAXED, __HIP_MEMORY_SCOPE_AGENT);
}

__global__ __launch_bounds__(NTHR) void lstm_main(
        const float* __restrict__ x, const float* __restrict__ Wi2h,
        const float* __restrict__ bi2h, const float* __restrict__ Wh2o,
        const float* __restrict__ bh2o, float* __restrict__ out,
        char* __restrict__ ws) {
    extern __shared__ char lds[];
    const int tid = threadIdx.x, wg = blockIdx.x;
    const int w = tid >> 6, lane = tid & 63, g = lane >> 4, nl = lane & 15;
    const int mt = w & 3, kh = w >> 2;   // wave: batch-tile mt, K-half kh

    // ---- phase 0: build this WG's W frags (cols = gate*1024 + wg*4 + j) ----
    for (int u = tid; u < 3072; u += NTHR) {          // u = akblk*16 + col
        int ak = u >> 4, cl = u & 15;
        int n = (cl >> 2) * 1024 + wg * 4 + (cl & 3);
        bf16x8 hi8, lo8;
#pragma unroll
        for (int j = 0; j < 8; ++j) {
            float v = Wi2h[(size_t)(ak * 8 + j) * 4096 + n];
            __bf16 h = (__bf16)v;
            hi8[j] = h;
            lo8[j] = (__bf16)(v - (float)h);
        }
        *(bf16x8*)(lds + L_WHI + (size_t)u * 16) = hi8;
        *(bf16x8*)(lds + L_WLO + (size_t)u * 16) = lo8;
    }
    const float bias_nl = bi2h[(nl >> 2) * 1024 + wg * 4 + (nl & 3)];
    __syncthreads();

    unsigned* flags = (unsigned*)(ws + WS_FLAGS);
    unsigned* go    = (unsigned*)(ws + WS_GO);
    float* exch  = (float*)(lds + L_EXCH);
    float* exch2 = (float*)(lds + L_EXCH2);
    float creg = 0.f;                      // c-state: threads tid<256 own (mt,row,hc)

#pragma unroll 1
    for (int t = 0; t < 512; ++t) {
        if (tid == 0) {
            while (__hip_atomic_load(go, __ATOMIC_RELAXED,
                                     __HIP_MEMORY_SCOPE_AGENT) < (unsigned)t)
                __builtin_amdgcn_s_sleep(1);
        }
        __syncthreads();
        __builtin_amdgcn_fence(__ATOMIC_ACQUIRE, "agent");  // inv L1/L2: fresh h

        const char* hb_rd = ws + WS_HBUF + (size_t)(t & 1) * HB_STRIDE;
        char*       hb_wr = ws + WS_HBUF + (size_t)((t + 1) & 1) * HB_STRIDE;
        f32x4 acc0 = {0.f, 0.f, 0.f, 0.f}, acc1 = {0.f, 0.f, 0.f, 0.f};

        if (kh == 0) {
            // ksteps 0..15: x part (f32 from global, hi/lo split in regs)
            const float* xb = x + ((size_t)(mt * 16 + nl) * 512 + t) * 512 + g * 8;
#pragma unroll 4
            for (int s = 0; s < 16; ++s) {
                float4 v0 = *(const float4*)(xb + s * 32);
                float4 v1 = *(const float4*)(xb + s * 32 + 4);
                float vv[8] = {v0.x, v0.y, v0.z, v0.w, v1.x, v1.y, v1.z, v1.w};
                bf16x8 ahi, alo;
#pragma unroll
                for (int j = 0; j < 8; ++j) {
                    __bf16 h = (__bf16)vv[j];
                    ahi[j] = h;
                    alo[j] = (__bf16)(vv[j] - (float)h);
                }
                const char* bp = lds + (size_t)(4 * s + g) * 256 + nl * 16;
                bf16x8 bhi = *(const bf16x8*)(bp + L_WHI);
                bf16x8 blo = *(const bf16x8*)(bp + L_WLO);
                if (s & 1) {
                    acc1 = __builtin_amdgcn_mfma_f32_16x16x32_bf16(ahi, bhi, acc1, 0, 0, 0);
                    acc1 = __builtin_amdgcn_mfma_f32_16x16x32_bf16(ahi, blo, acc1, 0, 0, 0);
                    acc1 = __builtin_amdgcn_mfma_f32_16x16x32_bf16(alo, bhi, acc1, 0, 0, 0);
                } else {
                    acc0 = __builtin_amdgcn_mfma_f32_16x16x32_bf16(ahi, bhi, acc0, 0, 0, 0);
                    acc0 = __builtin_amdgcn_mfma_f32_16x16x32_bf16(ahi, blo, acc0, 0, 0, 0);
                    acc0 = __builtin_amdgcn_mfma_f32_16x16x32_bf16(alo, bhi, acc0, 0, 0, 0);
                }
            }
            // ksteps 16..23: h part
#pragma unroll 4
            for (int s = 16; s < 24; ++s) {
                size_t ha = ((size_t)(mt * 32 + (s - 16)) * 64 + lane) * 16;
                bf16x8 ahi = *(const bf16x8*)(hb_rd + ha);
                bf16x8 alo = *(const bf16x8*)(hb_rd + HB_LO + ha);
                const char* bp = lds + (size_t)(4 * s + g) * 256 + nl * 16;
                bf16x8 bhi = *(const bf16x8*)(bp + L_WHI);
                bf16x8 blo = *(const bf16x8*)(bp + L_WLO);
                if (s & 1) {
                    acc1 = __builtin_amdgcn_mfma_f32_16x16x32_bf16(ahi, bhi, acc1, 0, 0, 0);
                    acc1 = __builtin_amdgcn_mfma_f32_16x16x32_bf16(ahi, blo, acc1, 0, 0, 0);
                    acc1 = __builtin_amdgcn_mfma_f32_16x16x32_bf16(alo, bhi, acc1, 0, 0, 0);
                } else {
                    acc0 = __builtin_amdgcn_mfma_f32_16x16x32_bf16(ahi, bhi, acc0, 0, 0, 0);
                    acc0 = __builtin_amdgcn_mfma_f32_16x16x32_bf16(ahi, blo, acc0, 0, 0, 0);
                    acc0 = __builtin_amdgcn_mfma_f32_16x16x32_bf16(alo, bhi, acc0, 0, 0, 0);
                }
            }
        } else {
            // ksteps 24..47: h part
#pragma unroll 4
            for (int s = 24; s < 48; ++s) {
                size_t ha = ((size_t)(mt * 32 + (s - 16)) * 64 + lane) * 16;
                bf16x8 ahi = *(const bf16x8*)(hb_rd + ha);
                bf16x8 alo = *(const bf16x8*)(hb_rd + HB_LO + ha);
                const char* bp = lds + (size_t)(4 * s + g) * 256 + nl * 16;
                bf16x8 bhi = *(const bf16x8*)(bp + L_WHI);
                bf16x8 blo = *(const bf16x8*)(bp + L_WLO);
                if (s & 1) {
                    acc1 = __builtin_amdgcn_mfma_f32_16x16x32_bf16(ahi, bhi, acc1, 0, 0, 0);
                    acc1 = __builtin_amdgcn_mfma_f32_16x16x32_bf16(ahi, blo, acc1, 0, 0, 0);
                    acc1 = __builtin_amdgcn_mfma_f32_16x16x32_bf16(alo, bhi, acc1, 0, 0, 0);
                } else {
                    acc0 = __builtin_amdgcn_mfma_f32_16x16x32_bf16(ahi, bhi, acc0, 0, 0, 0);
                    acc0 = __builtin_amdgcn_mfma_f32_16x16x32_bf16(ahi, blo, acc0, 0, 0, 0);
                    acc0 = __builtin_amdgcn_mfma_f32_16x16x32_bf16(alo, bhi, acc0, 0, 0, 0);
                }
            }
        }

        // ---- epilogue: K-half reduce, activations, cell update ----
        if (kh == 1) {
#pragma unroll
            for (int j = 0; j < 4; ++j)
                exch[mt * 256 + (g * 4 + j) * 16 + nl] = acc0[j] + acc1[j];
        }
        __syncthreads();
        if (kh == 0) {
#pragma unroll
            for (int j = 0; j < 4; ++j) {
                float pre = acc0[j] + acc1[j] + exch[mt * 256 + (g * 4 + j) * 16 + nl]
                          + bias_nl;
                float act = ((nl >> 2) == 2) ? tanh_f(pre) : sigm(pre);
                exch2[mt * 256 + (g * 4 + j) * 16 + nl] = act;
            }
        }
        __syncthreads();
        if (tid < 256) {
            int mt2 = tid >> 6, r = (tid >> 2) & 15, hc = tid & 3;
            const float* a2 = exch2 + mt2 * 256 + r * 16;
            float iv = a2[hc], fv = a2[4 + hc], gv = a2[8 + hc], ov = a2[12 + hc];
            float cc = fv * creg + iv * gv;
            creg = cc;
            float hv = ov * tanh_f(cc);
            __bf16 hh = (__bf16)hv;
            __bf16 hl = (__bf16)(hv - (float)hh);
            int k = 512 + wg * 4 + hc;
            int hs = (k >> 5) - 16, kg = (k >> 3) & 3, j8 = k & 7;
            uint32_t ad = ((uint32_t)(mt2 * 32 + hs) * 64 + kg * 16 + r) * 16 + j8 * 2;
            __hip_atomic_store((unsigned short*)(hb_wr + ad),
                               __builtin_bit_cast(unsigned short, hh),
                               __ATOMIC_RELAXED, __HIP_MEMORY_SCOPE_AGENT);
            __hip_atomic_store((unsigned short*)(hb_wr + HB_LO + ad),
                               __builtin_bit_cast(unsigned short, hl),
                               __ATOMIC_RELAXED, __HIP_MEMORY_SCOPE_AGENT);
            if (t == 511)
                __hip_atomic_store((float*)(ws + WS_HLAST)
                                       + (mt2 * 16 + r) * 1024 + wg * 4 + hc, hv,
                                   __ATOMIC_RELAXED, __HIP_MEMORY_SCOPE_AGENT);
        }
        __syncthreads();   // drains every wave's vmcnt -> h stores visible at L3
        if (tid == 0)
            __hip_atomic_store(&flags[wg], (unsigned)(t + 1),
                               __ATOMIC_RELAXED, __HIP_MEMORY_SCOPE_AGENT);
        if (wg == 0 && tid < 64) {
            unsigned tgt = (unsigned)(t + 1);
            for (;;) {
                unsigned f0 = __hip_atomic_load(flags + lane * 4 + 0, __ATOMIC_RELAXED, __HIP_MEMORY_SCOPE_AGENT);
                unsigned f1 = __hip_atomic_load(flags + lane * 4 + 1, __ATOMIC_RELAXED, __HIP_MEMORY_SCOPE_AGENT);
                unsigned f2 = __hip_atomic_load(flags + lane * 4 + 2, __ATOMIC_RELAXED, __HIP_MEMORY_SCOPE_AGENT);
                unsigned f3 = __hip_atomic_load(flags + lane * 4 + 3, __ATOMIC_RELAXED, __HIP_MEMORY_SCOPE_AGENT);
                unsigned mn = min(min(f0, f1), min(f2, f3));
                if (!__any(mn < tgt)) break;
                __builtin_amdgcn_s_sleep(1);
            }
            if (tid == 0)
                __hip_atomic_store(go, tgt, __ATOMIC_RELAXED, __HIP_MEMORY_SCOPE_AGENT);
        }
    }

    // ---- final projection: out = h_last @ W_h2o + b_h2o ----
    if (tid == 0) {
        while (__hip_atomic_load(go, __ATOMIC_RELAXED,
                                 __HIP_MEMORY_SCOPE_AGENT) < 512u)
            __builtin_amdgcn_s_sleep(1);
    }
    __syncthreads();
    __builtin_amdgcn_fence(__ATOMIC_ACQUIRE, "agent");

    const float* HL = (const float*)(ws + WS_HLAST);
    float* hl = (float*)lds;                       // 4 KB row stage
    float* pp = (float*)(lds + 8192);              // 2 KB partials
    int bb = wg & 63, q = wg >> 6;
    hl[tid]       = HL[bb * 1024 + tid];
    hl[tid + 512] = HL[bb * 1024 + 512 + tid];
    __syncthreads();
    int c = q * 128 + (tid & 127), kq = tid >> 7;
    const float* wc = Wh2o + c;
    float part = 0.f;
#pragma unroll 8
    for (int k = kq * 256; k < kq * 256 + 256; ++k)
        part += hl[k] * wc[(size_t)k * 512];
    pp[kq * 128 + (tid & 127)] = part;
    __syncthreads();
    if (tid < 128)
        out[bb * 512 + q * 128 + tid] =
            pp[tid] + pp[128 + tid] + pp[256 + tid] + pp[384 + tid] + bh2o[q * 128 + tid];
}

extern "C" void kernel_launch(void* const* d_in, const int* in_sizes, int n_in,
                              void* d_out, int out_size, void* d_ws, size_t ws_size,
                              hipStream_t stream) {
    const float* x    = (const float*)d_in[0];
    const float* Wi2h = (const float*)d_in[1];
    const float* bi2h = (const float*)d_in[2];
    const float* Wh2o = (const float*)d_in[3];
    const float* bh2o = (const float*)d_in[4];
    float* out = (float*)d_out;
    char* ws = (char*)d_ws;

    hipFuncSetAttribute(reinterpret_cast<const void*>(lstm_main),
                        hipFuncAttributeMaxDynamicSharedMemorySize, LDS_BYTES);

    lstm_init<<<256, 256, 0, stream>>>(ws);

    void* args[] = {(void*)&x, (void*)&Wi2h, (void*)&bi2h, (void*)&Wh2o,
                    (void*)&bh2o, (void*)&out, (void*)&ws};
    hipLaunchCooperativeKernel(reinterpret_cast<void*>(lstm_main),
                               dim3(NWG), dim3(NTHR), args, LDS_BYTES, stream);
}

// Round 6
// 5396.169 us; speedup vs baseline: 6.1675x; 2.3941x over previous
//
#include <hip/hip_runtime.h>
#include <hip/hip_bf16.h>
#include <stdint.h>

// LSTM B=64, T=512, IN=512, H=1024, K=1536, gates=4096.
// 256 WGs x 512 thr, cooperative. W (hi/lo bf16 frags) resident in LDS.
// Round 5: no per-step L2-invalidating fence. h read via agent-scope atomic
// b64 loads (MALL-served, per-access bypass); x via plain cached loads
// (L2 stays warm - never invalidated). x-part of GEMM computed BEFORE the
// go-spin to hide barrier latency. Numerics identical to round 4 (passed).

typedef __bf16 bf16x8 __attribute__((ext_vector_type(8)));
typedef float  f32x4  __attribute__((ext_vector_type(4)));
typedef unsigned long long u64;

#define NWG   256
#define NTHR  512

// workspace layout (bytes)
#define WS_FLAGS  0            // 256 * 4B monotonic step counters
#define WS_GO     2048         // 4B
#define WS_HBUF   4096         // 2 parities * 256 KB
#define HB_STRIDE 262144       // per parity: hi 128 KB + lo 128 KB
#define HB_LO     131072
#define WS_HLAST  (WS_HBUF + 2*HB_STRIDE)   // 64x1024 f32 = 256 KB

// LDS layout (dynamic)
#define L_WHI   0              // 192 akblk * 16 col * 8 bf16 = 48 KB
#define L_WLO   49152          // 48 KB
#define L_EXCH  98304          // 4 KB f32
#define L_EXCH2 102400         // 4 KB f32
#define LDS_BYTES 106496

__device__ __forceinline__ float sigm(float x) {
    return __builtin_amdgcn_rcpf(1.0f + __expf(-x));
}
__device__ __forceinline__ float tanh_f(float x) {
    x = fminf(fmaxf(x, -20.0f), 20.0f);
    float e = __expf(-2.0f * x);
    return (1.0f - e) * __builtin_amdgcn_rcpf(1.0f + e);
}

__global__ void lstm_init(char* __restrict__ ws) {
    // zero flags, go, and h-buffer parity 0 (266240 bytes = 66560 dwords)
    int id = blockIdx.x * 256 + threadIdx.x;
    for (int i = id; i < 66560; i += 256 * 256)
        __hip_atomic_store((unsigned*)ws + i, 0u,
                           __ATOMIC_RELAXED, __HIP_MEMORY_SCOPE_AGENT);
}

__global__ __launch_bounds__(NTHR) void lstm_main(
        const float* __restrict__ x, const float* __restrict__ Wi2h,
        const float* __restrict__ bi2h, const float* __restrict__ Wh2o,
        const float* __restrict__ bh2o, float* __restrict__ out,
        char* __restrict__ ws) {
    extern __shared__ char lds[];
    const int tid = threadIdx.x, wg = blockIdx.x;
    const int w = tid >> 6, lane = tid & 63, g = lane >> 4, nl = lane & 15;
    const int mt = w & 3, kh = w >> 2;   // wave: batch-tile mt, K-half kh

    // ---- phase 0: build this WG's W frags (cols = gate*1024 + wg*4 + j) ----
    for (int u = tid; u < 3072; u += NTHR) {          // u = akblk*16 + col
        int ak = u >> 4, cl = u & 15;
        int n = (cl >> 2) * 1024 + wg * 4 + (cl & 3);
        bf16x8 hi8, lo8;
#pragma unroll
        for (int j = 0; j < 8; ++j) {
            float v = Wi2h[(size_t)(ak * 8 + j) * 4096 + n];
            __bf16 h = (__bf16)v;
            hi8[j] = h;
            lo8[j] = (__bf16)(v - (float)h);
        }
        *(bf16x8*)(lds + L_WHI + (size_t)u * 16) = hi8;
        *(bf16x8*)(lds + L_WLO + (size_t)u * 16) = lo8;
    }
    const float bias_nl = bi2h[(nl >> 2) * 1024 + wg * 4 + (nl & 3)];
    __syncthreads();

    unsigned* flags = (unsigned*)(ws + WS_FLAGS);
    unsigned* go    = (unsigned*)(ws + WS_GO);
    float* exch  = (float*)(lds + L_EXCH);
    float* exch2 = (float*)(lds + L_EXCH2);
    float creg = 0.f;                      // c-state: threads tid<256 own (mt,row,hc)

#pragma unroll 1
    for (int t = 0; t < 512; ++t) {
        const char* hb_rd = ws + WS_HBUF + (size_t)(t & 1) * HB_STRIDE;
        char*       hb_wr = ws + WS_HBUF + (size_t)((t + 1) & 1) * HB_STRIDE;
        f32x4 acc0 = {0.f, 0.f, 0.f, 0.f}, acc1 = {0.f, 0.f, 0.f, 0.f};

        // ---- x-part FIRST (no dependence on h_{t-1}): 8 ksteps per K-half ----
        {
            const float* xb = x + ((size_t)(mt * 16 + nl) * 512 + t) * 512 + g * 8;
            const int s0 = kh * 8;
#pragma unroll
            for (int si = 0; si < 8; ++si) {
                const int s = s0 + si;
                float4 v0 = *(const float4*)(xb + s * 32);
                float4 v1 = *(const float4*)(xb + s * 32 + 4);
                float vv[8] = {v0.x, v0.y, v0.z, v0.w, v1.x, v1.y, v1.z, v1.w};
                bf16x8 ahi, alo;
#pragma unroll
                for (int j = 0; j < 8; ++j) {
                    __bf16 h = (__bf16)vv[j];
                    ahi[j] = h;
                    alo[j] = (__bf16)(vv[j] - (float)h);
                }
                const char* bp = lds + (size_t)(4 * s + g) * 256 + nl * 16;
                bf16x8 bhi = *(const bf16x8*)(bp + L_WHI);
                bf16x8 blo = *(const bf16x8*)(bp + L_WLO);
                if (s & 1) {
                    acc1 = __builtin_amdgcn_mfma_f32_16x16x32_bf16(ahi, bhi, acc1, 0, 0, 0);
                    acc1 = __builtin_amdgcn_mfma_f32_16x16x32_bf16(ahi, blo, acc1, 0, 0, 0);
                    acc1 = __builtin_amdgcn_mfma_f32_16x16x32_bf16(alo, bhi, acc1, 0, 0, 0);
                } else {
                    acc0 = __builtin_amdgcn_mfma_f32_16x16x32_bf16(ahi, bhi, acc0, 0, 0, 0);
                    acc0 = __builtin_amdgcn_mfma_f32_16x16x32_bf16(ahi, blo, acc0, 0, 0, 0);
                    acc0 = __builtin_amdgcn_mfma_f32_16x16x32_bf16(alo, bhi, acc0, 0, 0, 0);
                }
            }
        }

        // ---- wait until all WGs finished step t-1 (h_{t-1} visible) ----
        if (tid == 0) {
            while (__hip_atomic_load(go, __ATOMIC_RELAXED,
                                     __HIP_MEMORY_SCOPE_AGENT) < (unsigned)t)
                __builtin_amdgcn_s_sleep(1);
        }
        __syncthreads();

        // ---- h-part: 16 ksteps per K-half, agent-scope atomic b64 loads ----
        {
            const int s0 = 16 + kh * 16;
#pragma unroll 4
            for (int si = 0; si < 16; ++si) {
                const int s = s0 + si;
                size_t ha = ((size_t)(mt * 32 + (s - 16)) * 64 + lane) * 16;
                const char* bse = hb_rd + ha;
                u64 q0 = __hip_atomic_load((const u64*)(bse),
                           __ATOMIC_RELAXED, __HIP_MEMORY_SCOPE_AGENT);
                u64 q1 = __hip_atomic_load((const u64*)(bse + 8),
                           __ATOMIC_RELAXED, __HIP_MEMORY_SCOPE_AGENT);
                u64 q2 = __hip_atomic_load((const u64*)(bse + HB_LO),
                           __ATOMIC_RELAXED, __HIP_MEMORY_SCOPE_AGENT);
                u64 q3 = __hip_atomic_load((const u64*)(bse + HB_LO + 8),
                           __ATOMIC_RELAXED, __HIP_MEMORY_SCOPE_AGENT);
                union { u64 q[2]; bf16x8 v; } uh, ul;
                uh.q[0] = q0; uh.q[1] = q1;
                ul.q[0] = q2; ul.q[1] = q3;
                bf16x8 ahi = uh.v, alo = ul.v;
                const char* bp = lds + (size_t)(4 * s + g) * 256 + nl * 16;
                bf16x8 bhi = *(const bf16x8*)(bp + L_WHI);
                bf16x8 blo = *(const bf16x8*)(bp + L_WLO);
                if (s & 1) {
                    acc1 = __builtin_amdgcn_mfma_f32_16x16x32_bf16(ahi, bhi, acc1, 0, 0, 0);
                    acc1 = __builtin_amdgcn_mfma_f32_16x16x32_bf16(ahi, blo, acc1, 0, 0, 0);
                    acc1 = __builtin_amdgcn_mfma_f32_16x16x32_bf16(alo, bhi, acc1, 0, 0, 0);
                } else {
                    acc0 = __builtin_amdgcn_mfma_f32_16x16x32_bf16(ahi, bhi, acc0, 0, 0, 0);
                    acc0 = __builtin_amdgcn_mfma_f32_16x16x32_bf16(ahi, blo, acc0, 0, 0, 0);
                    acc0 = __builtin_amdgcn_mfma_f32_16x16x32_bf16(alo, bhi, acc0, 0, 0, 0);
                }
            }
        }

        // ---- epilogue: K-half reduce, activations, cell update ----
        if (kh == 1) {
#pragma unroll
            for (int j = 0; j < 4; ++j)
                exch[mt * 256 + (g * 4 + j) * 16 + nl] = acc0[j] + acc1[j];
        }
        __syncthreads();
        if (kh == 0) {
#pragma unroll
            for (int j = 0; j < 4; ++j) {
                float pre = acc0[j] + acc1[j] + exch[mt * 256 + (g * 4 + j) * 16 + nl]
                          + bias_nl;
                float act = ((nl >> 2) == 2) ? tanh_f(pre) : sigm(pre);
                exch2[mt * 256 + (g * 4 + j) * 16 + nl] = act;
            }
        }
        __syncthreads();
        if (tid < 256) {
            int mt2 = tid >> 6, r = (tid >> 2) & 15, hc = tid & 3;
            const float* a2 = exch2 + mt2 * 256 + r * 16;
            float iv = a2[hc], fv = a2[4 + hc], gv = a2[8 + hc], ov = a2[12 + hc];
            float cc = fv * creg + iv * gv;
            creg = cc;
            float hv = ov * tanh_f(cc);
            __bf16 hh = (__bf16)hv;
            __bf16 hl = (__bf16)(hv - (float)hh);
            int k = 512 + wg * 4 + hc;
            int hs = (k >> 5) - 16, kg = (k >> 3) & 3, j8 = k & 7;
            uint32_t ad = ((uint32_t)(mt2 * 32 + hs) * 64 + kg * 16 + r) * 16 + j8 * 2;
            __hip_atomic_store((unsigned short*)(hb_wr + ad),
                               __builtin_bit_cast(unsigned short, hh),
                               __ATOMIC_RELAXED, __HIP_MEMORY_SCOPE_AGENT);
            __hip_atomic_store((unsigned short*)(hb_wr + HB_LO + ad),
                               __builtin_bit_cast(unsigned short, hl),
                               __ATOMIC_RELAXED, __HIP_MEMORY_SCOPE_AGENT);
            if (t == 511)
                __hip_atomic_store((float*)(ws + WS_HLAST)
                                       + (mt2 * 16 + r) * 1024 + wg * 4 + hc, hv,
                                   __ATOMIC_RELAXED, __HIP_MEMORY_SCOPE_AGENT);
        }
        __syncthreads();   // drains every wave's vmcnt -> h stores visible at MALL
        if (tid == 0)
            __hip_atomic_store(&flags[wg], (unsigned)(t + 1),
                               __ATOMIC_RELAXED, __HIP_MEMORY_SCOPE_AGENT);
        if (wg == 0 && tid < 64) {
            unsigned tgt = (unsigned)(t + 1);
            for (;;) {
                unsigned f0 = __hip_atomic_load(flags + lane * 4 + 0, __ATOMIC_RELAXED, __HIP_MEMORY_SCOPE_AGENT);
                unsigned f1 = __hip_atomic_load(flags + lane * 4 + 1, __ATOMIC_RELAXED, __HIP_MEMORY_SCOPE_AGENT);
                unsigned f2 = __hip_atomic_load(flags + lane * 4 + 2, __ATOMIC_RELAXED, __HIP_MEMORY_SCOPE_AGENT);
                unsigned f3 = __hip_atomic_load(flags + lane * 4 + 3, __ATOMIC_RELAXED, __HIP_MEMORY_SCOPE_AGENT);
                unsigned mn = min(min(f0, f1), min(f2, f3));
                if (!__any(mn < tgt)) break;
                __builtin_amdgcn_s_sleep(1);
            }
            if (tid == 0)
                __hip_atomic_store(go, tgt, __ATOMIC_RELAXED, __HIP_MEMORY_SCOPE_AGENT);
        }
    }

    // ---- final projection: out = h_last @ W_h2o + b_h2o ----
    if (tid == 0) {
        while (__hip_atomic_load(go, __ATOMIC_RELAXED,
                                 __HIP_MEMORY_SCOPE_AGENT) < 512u)
            __builtin_amdgcn_s_sleep(1);
    }
    __syncthreads();
    __builtin_amdgcn_fence(__ATOMIC_ACQUIRE, "agent");   // once, outside hot loop

    const float* HL = (const float*)(ws + WS_HLAST);
    float* hl = (float*)lds;                       // 4 KB row stage
    float* pp = (float*)(lds + 8192);              // 2 KB partials
    int bb = wg & 63, q = wg >> 6;
    hl[tid]       = HL[bb * 1024 + tid];
    hl[tid + 512] = HL[bb * 1024 + 512 + tid];
    __syncthreads();
    int c = q * 128 + (tid & 127), kq = tid >> 7;
    const float* wc = Wh2o + c;
    float part = 0.f;
#pragma unroll 8
    for (int k = kq * 256; k < kq * 256 + 256; ++k)
        part += hl[k] * wc[(size_t)k * 512];
    pp[kq * 128 + (tid & 127)] = part;
    __syncthreads();
    if (tid < 128)
        out[bb * 512 + q * 128 + tid] =
            pp[tid] + pp[128 + tid] + pp[256 + tid] + pp[384 + tid] + bh2o[q * 128 + tid];
}

extern "C" void kernel_launch(void* const* d_in, const int* in_sizes, int n_in,
                              void* d_out, int out_size, void* d_ws, size_t ws_size,
                              hipStream_t stream) {
    const float* x    = (const float*)d_in[0];
    const float* Wi2h = (const float*)d_in[1];
    const float* bi2h = (const float*)d_in[2];
    const float* Wh2o = (const float*)d_in[3];
    const float* bh2o = (const float*)d_in[4];
    float* out = (float*)d_out;
    char* ws = (char*)d_ws;

    hipFuncSetAttribute(reinterpret_cast<const void*>(lstm_main),
                        hipFuncAttributeMaxDynamicSharedMemorySize, LDS_BYTES);

    lstm_init<<<256, 256, 0, stream>>>(ws);

    void* args[] = {(void*)&x, (void*)&Wi2h, (void*)&bi2h, (void*)&Wh2o,
                    (void*)&bh2o, (void*)&out, (void*)&ws};
    hipLaunchCooperativeKernel(reinterpret_cast<void*>(lstm_main),
                               dim3(NWG), dim3(NTHR), args, LDS_BYTES, stream);
}

// Round 8
// 5292.912 us; speedup vs baseline: 6.2878x; 1.0195x over previous
//
#include <hip/hip_runtime.h>
#include <hip/hip_bf16.h>
#include <stdint.h>

// LSTM B=64, T=512, IN=512, H=1024, K=1536, gates=4096.
// 256 WGs x 512 thr, cooperative. W (hi/lo bf16 frags) resident in LDS.
// Round 7: remove go-word hot-line contention. Aggregator (wg0 wave0) fans
// out the release value to 256 per-WG mailboxes (64B-spaced); each WG polls
// only its own line. h loads agent-scope (proven correct r5/r6); x plain
// cached; x-part GEMM before the release-wait hides barrier latency.

typedef __bf16 bf16x8 __attribute__((ext_vector_type(8)));
typedef float  f32x4  __attribute__((ext_vector_type(4)));
typedef unsigned long long u64;

#define NWG   256
#define NTHR  512

// workspace layout (bytes)
#define WS_FLAGS  0            // 256 * 4B monotonic step counters
#define WS_GOMB   1024         // 256 mailboxes, 64B apart (16 KB)
#define WS_HBUF   17408        // 2 parities * 256 KB
#define HB_STRIDE 262144       // per parity: hi 128 KB + lo 128 KB
#define HB_LO     131072
#define WS_HLAST  (WS_HBUF + 2*HB_STRIDE)   // 64x1024 f32 = 256 KB

// LDS layout (dynamic)
#define L_WHI   0              // 192 akblk * 16 col * 8 bf16 = 48 KB
#define L_WLO   49152          // 48 KB
#define L_EXCH  98304          // 4 KB f32
#define L_EXCH2 102400         // 4 KB f32
#define LDS_BYTES 106496

__device__ __forceinline__ float sigm(float x) {
    return __builtin_amdgcn_rcpf(1.0f + __expf(-x));
}
__device__ __forceinline__ float tanh_f(float x) {
    x = fminf(fmaxf(x, -20.0f), 20.0f);
    float e = __expf(-2.0f * x);
    return (1.0f - e) * __builtin_amdgcn_rcpf(1.0f + e);
}

__global__ void lstm_init(char* __restrict__ ws) {
    // zero flags+mailboxes ([0,17408) = 4352 dwords) and h parity 0
    // ([17408, 17408+262144) = 65536 dwords) -> dwords [0, 69888)
    int id = blockIdx.x * 256 + threadIdx.x;
    for (int i = id; i < 69888; i += 256 * 256)
        __hip_atomic_store((unsigned*)ws + i, 0u,
                           __ATOMIC_RELAXED, __HIP_MEMORY_SCOPE_AGENT);
}

__global__ __launch_bounds__(NTHR) void lstm_main(
        const float* __restrict__ x, const float* __restrict__ Wi2h,
        const float* __restrict__ bi2h, const float* __restrict__ Wh2o,
        const float* __restrict__ bh2o, float* __restrict__ out,
        char* __restrict__ ws) {
    extern __shared__ char lds[];
    const int tid = threadIdx.x, wg = blockIdx.x;
    const int w = tid >> 6, lane = tid & 63, g = lane >> 4, nl = lane & 15;
    const int mt = w & 3, kh = w >> 2;   // wave: batch-tile mt, K-half kh

    // ---- phase 0: build this WG's W frags (cols = gate*1024 + wg*4 + j) ----
    for (int u = tid; u < 3072; u += NTHR) {          // u = akblk*16 + col
        int ak = u >> 4, cl = u & 15;
        int n = (cl >> 2) * 1024 + wg * 4 + (cl & 3);
        bf16x8 hi8, lo8;
#pragma unroll
        for (int j = 0; j < 8; ++j) {
            float v = Wi2h[(size_t)(ak * 8 + j) * 4096 + n];
            __bf16 h = (__bf16)v;
            hi8[j] = h;
            lo8[j] = (__bf16)(v - (float)h);
        }
        *(bf16x8*)(lds + L_WHI + (size_t)u * 16) = hi8;
        *(bf16x8*)(lds + L_WLO + (size_t)u * 16) = lo8;
    }
    const float bias_nl = bi2h[(nl >> 2) * 1024 + wg * 4 + (nl & 3)];
    __syncthreads();

    unsigned* flags = (unsigned*)(ws + WS_FLAGS);
    unsigned* my_mb = (unsigned*)(ws + WS_GOMB) + wg * 16;   // own 64B line
    float* exch  = (float*)(lds + L_EXCH);
    float* exch2 = (float*)(lds + L_EXCH2);
    float creg = 0.f;                      // c-state: threads tid<256 own (mt,row,hc)

#pragma unroll 1
    for (int t = 0; t < 512; ++t) {
        const char* hb_rd = ws + WS_HBUF + (size_t)(t & 1) * HB_STRIDE;
        char*       hb_wr = ws + WS_HBUF + (size_t)((t + 1) & 1) * HB_STRIDE;
        f32x4 acc0 = {0.f, 0.f, 0.f, 0.f}, acc1 = {0.f, 0.f, 0.f, 0.f};

        // ---- x-part FIRST (no dependence on h_{t-1}): 8 ksteps per K-half ----
        {
            const float* xb = x + ((size_t)(mt * 16 + nl) * 512 + t) * 512 + g * 8;
            const int s0 = kh * 8;
#pragma unroll
            for (int si = 0; si < 8; ++si) {
                const int s = s0 + si;
                float4 v0 = *(const float4*)(xb + s * 32);
                float4 v1 = *(const float4*)(xb + s * 32 + 4);
                float vv[8] = {v0.x, v0.y, v0.z, v0.w, v1.x, v1.y, v1.z, v1.w};
                bf16x8 ahi, alo;
#pragma unroll
                for (int j = 0; j < 8; ++j) {
                    __bf16 h = (__bf16)vv[j];
                    ahi[j] = h;
                    alo[j] = (__bf16)(vv[j] - (float)h);
                }
                const char* bp = lds + (size_t)(4 * s + g) * 256 + nl * 16;
                bf16x8 bhi = *(const bf16x8*)(bp + L_WHI);
                bf16x8 blo = *(const bf16x8*)(bp + L_WLO);
                if (s & 1) {
                    acc1 = __builtin_amdgcn_mfma_f32_16x16x32_bf16(ahi, bhi, acc1, 0, 0, 0);
                    acc1 = __builtin_amdgcn_mfma_f32_16x16x32_bf16(ahi, blo, acc1, 0, 0, 0);
                    acc1 = __builtin_amdgcn_mfma_f32_16x16x32_bf16(alo, bhi, acc1, 0, 0, 0);
                } else {
                    acc0 = __builtin_amdgcn_mfma_f32_16x16x32_bf16(ahi, bhi, acc0, 0, 0, 0);
                    acc0 = __builtin_amdgcn_mfma_f32_16x16x32_bf16(ahi, blo, acc0, 0, 0, 0);
                    acc0 = __builtin_amdgcn_mfma_f32_16x16x32_bf16(alo, bhi, acc0, 0, 0, 0);
                }
            }
        }

        // ---- wait own mailbox: all WGs finished step t-1 (h_{t-1} visible) ----
        if (tid == 0) {
            while (__hip_atomic_load(my_mb, __ATOMIC_RELAXED,
                                     __HIP_MEMORY_SCOPE_AGENT) < (unsigned)t) {}
        }
        __syncthreads();

        // ---- h-part: 16 ksteps per K-half, agent-scope atomic b64 loads ----
        {
            const int s0 = 16 + kh * 16;
#pragma unroll 8
            for (int si = 0; si < 16; ++si) {
                const int s = s0 + si;
                size_t ha = ((size_t)(mt * 32 + (s - 16)) * 64 + lane) * 16;
                const char* bse = hb_rd + ha;
                u64 q0 = __hip_atomic_load((const u64*)(bse),
                           __ATOMIC_RELAXED, __HIP_MEMORY_SCOPE_AGENT);
                u64 q1 = __hip_atomic_load((const u64*)(bse + 8),
                           __ATOMIC_RELAXED, __HIP_MEMORY_SCOPE_AGENT);
                u64 q2 = __hip_atomic_load((const u64*)(bse + HB_LO),
                           __ATOMIC_RELAXED, __HIP_MEMORY_SCOPE_AGENT);
                u64 q3 = __hip_atomic_load((const u64*)(bse + HB_LO + 8),
                           __ATOMIC_RELAXED, __HIP_MEMORY_SCOPE_AGENT);
                union { u64 q[2]; bf16x8 v; } uh, ul;
                uh.q[0] = q0; uh.q[1] = q1;
                ul.q[0] = q2; ul.q[1] = q3;
                bf16x8 ahi = uh.v, alo = ul.v;
                const char* bp = lds + (size_t)(4 * s + g) * 256 + nl * 16;
                bf16x8 bhi = *(const bf16x8*)(bp + L_WHI);
                bf16x8 blo = *(const bf16x8*)(bp + L_WLO);
                if (s & 1) {
                    acc1 = __builtin_amdgcn_mfma_f32_16x16x32_bf16(ahi, bhi, acc1, 0, 0, 0);
                    acc1 = __builtin_amdgcn_mfma_f32_16x16x32_bf16(ahi, blo, acc1, 0, 0, 0);
                    acc1 = __builtin_amdgcn_mfma_f32_16x16x32_bf16(alo, bhi, acc1, 0, 0, 0);
                } else {
                    acc0 = __builtin_amdgcn_mfma_f32_16x16x32_bf16(ahi, bhi, acc0, 0, 0, 0);
                    acc0 = __builtin_amdgcn_mfma_f32_16x16x32_bf16(ahi, blo, acc0, 0, 0, 0);
                    acc0 = __builtin_amdgcn_mfma_f32_16x16x32_bf16(alo, bhi, acc0, 0, 0, 0);
                }
            }
        }

        // ---- epilogue: K-half reduce, activations, cell update ----
        if (kh == 1) {
#pragma unroll
            for (int j = 0; j < 4; ++j)
                exch[mt * 256 + (g * 4 + j) * 16 + nl] = acc0[j] + acc1[j];
        }
        __syncthreads();
        if (kh == 0) {
#pragma unroll
            for (int j = 0; j < 4; ++j) {
                float pre = acc0[j] + acc1[j] + exch[mt * 256 + (g * 4 + j) * 16 + nl]
                          + bias_nl;
                float act = ((nl >> 2) == 2) ? tanh_f(pre) : sigm(pre);
                exch2[mt * 256 + (g * 4 + j) * 16 + nl] = act;
            }
        }
        __syncthreads();
        if (tid < 256) {
            int mt2 = tid >> 6, r = (tid >> 2) & 15, hc = tid & 3;
            const float* a2 = exch2 + mt2 * 256 + r * 16;
            float iv = a2[hc], fv = a2[4 + hc], gv = a2[8 + hc], ov = a2[12 + hc];
            float cc = fv * creg + iv * gv;
            creg = cc;
            float hv = ov * tanh_f(cc);
            __bf16 hh = (__bf16)hv;
            __bf16 hl = (__bf16)(hv - (float)hh);
            int k = 512 + wg * 4 + hc;
            int hs = (k >> 5) - 16, kg = (k >> 3) & 3, j8 = k & 7;
            uint32_t ad = ((uint32_t)(mt2 * 32 + hs) * 64 + kg * 16 + r) * 16 + j8 * 2;
            __hip_atomic_store((unsigned short*)(hb_wr + ad),
                               __builtin_bit_cast(unsigned short, hh),
                               __ATOMIC_RELAXED, __HIP_MEMORY_SCOPE_AGENT);
            __hip_atomic_store((unsigned short*)(hb_wr + HB_LO + ad),
                               __builtin_bit_cast(unsigned short, hl),
                               __ATOMIC_RELAXED, __HIP_MEMORY_SCOPE_AGENT);
            if (t == 511)
                __hip_atomic_store((float*)(ws + WS_HLAST)
                                       + (mt2 * 16 + r) * 1024 + wg * 4 + hc, hv,
                                   __ATOMIC_RELAXED, __HIP_MEMORY_SCOPE_AGENT);
        }
        __syncthreads();   // drains every wave's vmcnt -> h stores visible at MALL
        if (tid == 0)
            __hip_atomic_store(&flags[wg], (unsigned)(t + 1),
                               __ATOMIC_RELAXED, __HIP_MEMORY_SCOPE_AGENT);
        // ---- aggregator: wg0 wave0 scans flags, fans out to mailboxes ----
        if (wg == 0 && w == 0) {
            unsigned tgt = (unsigned)(t + 1);
            const u64* f64 = (const u64*)flags;
            for (;;) {
                u64 a = __hip_atomic_load(f64 + 2 * lane,
                          __ATOMIC_RELAXED, __HIP_MEMORY_SCOPE_AGENT);
                u64 b = __hip_atomic_load(f64 + 2 * lane + 1,
                          __ATOMIC_RELAXED, __HIP_MEMORY_SCOPE_AGENT);
                unsigned m0 = min(min((unsigned)a, (unsigned)(a >> 32)),
                                  min((unsigned)b, (unsigned)(b >> 32)));
                if (__all(m0 >= tgt)) break;
            }
            unsigned* mb = (unsigned*)(ws + WS_GOMB);
#pragma unroll
            for (int q = 0; q < 4; ++q)
                __hip_atomic_store(mb + (q * 64 + lane) * 16, tgt,
                                   __ATOMIC_RELAXED, __HIP_MEMORY_SCOPE_AGENT);
        }
    }

    // ---- final projection: out = h_last @ W_h2o + b_h2o ----
    if (tid == 0) {
        while (__hip_atomic_load(my_mb, __ATOMIC_RELAXED,
                                 __HIP_MEMORY_SCOPE_AGENT) < 512u) {}
    }
    __syncthreads();
    __builtin_amdgcn_fence(__ATOMIC_ACQUIRE, "agent");   // once, outside hot loop

    const float* HL = (const float*)(ws + WS_HLAST);
    float* hl = (float*)lds;                       // 4 KB row stage
    float* pp = (float*)(lds + 8192);              // 2 KB partials
    int bb = wg & 63, q = wg >> 6;
    hl[tid]       = HL[bb * 1024 + tid];
    hl[tid + 512] = HL[bb * 1024 + 512 + tid];
    __syncthreads();
    int c = q * 128 + (tid & 127), kq = tid >> 7;
    const float* wc = Wh2o + c;
    float part = 0.f;
#pragma unroll 8
    for (int k = kq * 256; k < kq * 256 + 256; ++k)
        part += hl[k] * wc[(size_t)k * 512];
    pp[kq * 128 + (tid & 127)] = part;
    __syncthreads();
    if (tid < 128)
        out[bb * 512 + q * 128 + tid] =
            pp[tid] + pp[128 + tid] + pp[256 + tid] + pp[384 + tid] + bh2o[q * 128 + tid];
}

extern "C" void kernel_launch(void* const* d_in, const int* in_sizes, int n_in,
                              void* d_out, int out_size, void* d_ws, size_t ws_size,
                              hipStream_t stream) {
    const float* x    = (const float*)d_in[0];
    const float* Wi2h = (const float*)d_in[1];
    const float* bi2h = (const float*)d_in[2];
    const float* Wh2o = (const float*)d_in[3];
    const float* bh2o = (const float*)d_in[4];
    float* out = (float*)d_out;
    char* ws = (char*)d_ws;

    hipFuncSetAttribute(reinterpret_cast<const void*>(lstm_main),
                        hipFuncAttributeMaxDynamicSharedMemorySize, LDS_BYTES);

    lstm_init<<<256, 256, 0, stream>>>(ws);

    void* args[] = {(void*)&x, (void*)&Wi2h, (void*)&bi2h, (void*)&Wh2o,
                    (void*)&bh2o, (void*)&out, (void*)&ws};
    hipLaunchCooperativeKernel(reinterpret_cast<void*>(lstm_main),
                               dim3(NWG), dim3(NTHR), args, LDS_BYTES, stream);
}

// Round 10
// 4514.895 us; speedup vs baseline: 7.3713x; 1.1723x over previous
//
#include <hip/hip_runtime.h>
#include <hip/hip_bf16.h>
#include <stdint.h>

// LSTM B=64, T=512, IN=512, H=1024, K=1536, gates=4096.
// 256 WGs x 512 thr, cooperative. W (hi/lo bf16 frags) resident in LDS.
// Round 9: XCD-local h staging. Per step each XCD's 32 WGs copy the 256KB
// h-image from MALL (agent b64 loads, 8KB slice/WG) into a per-XCD stage
// buffer (plain stores -> local L2). All WGs then read h from local L2 via
// inline-asm global_load_dwordx4 sc0 (L1-bypass) with counted-vmcnt double
// batching. MALL h-traffic: 64MB -> 2MB/step. Mailbox barrier unchanged.

typedef __bf16 bf16x8 __attribute__((ext_vector_type(8)));
typedef float  f32x4  __attribute__((ext_vector_type(4)));
typedef unsigned long long u64;

#define NWG   256
#define NTHR  512

// workspace layout (bytes)
#define WS_FLAGS   0           // 256*4 monotonic step counters
#define WS_GOMB    1024        // 256 mailboxes, 64B apart
#define WS_XCDC    17408       // 8 registration counters, 64B apart
#define WS_SCNT    17920       // 8 stage monotonic counters, 64B apart
#define WS_SFLAG   18432       // 8 stage release flags, 64B apart
#define WS_HBUF    20480       // 2 parities * 256 KB
#define HB_STRIDE  262144
#define HB_LO      131072
#define WS_HLAST   544768      // 64x1024 f32
#define WS_STAGE   806912      // 8 XCD * 2 parities * 256 KB = 4 MB
#define STG_STRIDE 262144

// LDS layout (dynamic)
#define L_WHI   0
#define L_WLO   49152
#define L_EXCH  98304
#define L_EXCH2 102400
#define LDS_BYTES 106496

__device__ __forceinline__ float sigm(float x) {
    return __builtin_amdgcn_rcpf(1.0f + __expf(-x));
}
__device__ __forceinline__ float tanh_f(float x) {
    x = fminf(fmaxf(x, -20.0f), 20.0f);
    float e = __expf(-2.0f * x);
    return (1.0f - e) * __builtin_amdgcn_rcpf(1.0f + e);
}

__global__ void lstm_init(char* __restrict__ ws) {
    // zero flags/mailboxes/counters/stageflags + both h parities:
    // bytes [0, 544768) = 136192 dwords
    int id = blockIdx.x * 256 + threadIdx.x;
    for (int i = id; i < 136192; i += 256 * 256)
        __hip_atomic_store((unsigned*)ws + i, 0u,
                           __ATOMIC_RELAXED, __HIP_MEMORY_SCOPE_AGENT);
}

// ---- macros for the per-step phases (si must be compile-time) ----
#define X_HALF(A)                                                              \
  { _Pragma("unroll")                                                          \
    for (int si = (A); si < (A) + 4; ++si) {                                   \
      const int s = kh * 8 + si;                                               \
      float4 v0 = *(const float4*)(xb + s * 32);                               \
      float4 v1 = *(const float4*)(xb + s * 32 + 4);                           \
      float vv[8] = {v0.x, v0.y, v0.z, v0.w, v1.x, v1.y, v1.z, v1.w};          \
      bf16x8 ahi, alo;                                                         \
      _Pragma("unroll")                                                        \
      for (int j = 0; j < 8; ++j) {                                            \
        __bf16 hh_ = (__bf16)vv[j];                                            \
        ahi[j] = hh_;                                                          \
        alo[j] = (__bf16)(vv[j] - (float)hh_);                                 \
      }                                                                        \
      const char* bp = lds + (size_t)(4 * s + g) * 256 + nl * 16;              \
      bf16x8 bhi = *(const bf16x8*)(bp + L_WHI);                               \
      bf16x8 blo = *(const bf16x8*)(bp + L_WLO);                               \
      if (si & 1) {                                                            \
        acc1 = __builtin_amdgcn_mfma_f32_16x16x32_bf16(ahi, bhi, acc1, 0, 0, 0);\
        acc1 = __builtin_amdgcn_mfma_f32_16x16x32_bf16(ahi, blo, acc1, 0, 0, 0);\
        acc1 = __builtin_amdgcn_mfma_f32_16x16x32_bf16(alo, bhi, acc1, 0, 0, 0);\
      } else {                                                                 \
        acc0 = __builtin_amdgcn_mfma_f32_16x16x32_bf16(ahi, bhi, acc0, 0, 0, 0);\
        acc0 = __builtin_amdgcn_mfma_f32_16x16x32_bf16(ahi, blo, acc0, 0, 0, 0);\
        acc0 = __builtin_amdgcn_mfma_f32_16x16x32_bf16(alo, bhi, acc0, 0, 0, 0);\
      }                                                                        \
    } }

#define ISSUE(B)                                                               \
  { _Pragma("unroll")                                                          \
    for (int si = 4 * (B); si < 4 * (B) + 4; ++si) {                           \
      uint64_t a0 = (uint64_t)(sb + habase + si * 1024);                       \
      asm volatile("global_load_dwordx4 %0, %1, off sc0"                       \
                   : "=v"(vh[si]) : "v"(a0) : "memory");                       \
      uint64_t a1 = a0 + 131072;                                               \
      asm volatile("global_load_dwordx4 %0, %1, off sc0"                       \
                   : "=v"(vl[si]) : "v"(a1) : "memory");                       \
    } }

#define WAITV(N)                                                               \
  do { asm volatile("s_waitcnt vmcnt(" #N ")" ::: "memory");                   \
       __builtin_amdgcn_sched_barrier(0); } while (0)

#define COMPB(B)                                                               \
  { _Pragma("unroll")                                                          \
    for (int si = 4 * (B); si < 4 * (B) + 4; ++si) {                           \
      union UU { float4 f; bf16x8 b; };                                        \
      UU uh, ul;                                                               \
      uh.f = vh[si];                                                           \
      ul.f = vl[si];                                                           \
      bf16x8 ahi = uh.b, alo = ul.b;                                           \
      const char* bp = lds + (size_t)(64 + kh * 64 + 4 * si + g) * 256 + nl * 16;\
      bf16x8 bhi = *(const bf16x8*)(bp + L_WHI);                               \
      bf16x8 blo = *(const bf16x8*)(bp + L_WLO);                               \
      if (si & 1) {                                                            \
        acc1 = __builtin_amdgcn_mfma_f32_16x16x32_bf16(ahi, bhi, acc1, 0, 0, 0);\
        acc1 = __builtin_amdgcn_mfma_f32_16x16x32_bf16(ahi, blo, acc1, 0, 0, 0);\
        acc1 = __builtin_amdgcn_mfma_f32_16x16x32_bf16(alo, bhi, acc1, 0, 0, 0);\
      } else {                                                                 \
        acc0 = __builtin_amdgcn_mfma_f32_16x16x32_bf16(ahi, bhi, acc0, 0, 0, 0);\
        acc0 = __builtin_amdgcn_mfma_f32_16x16x32_bf16(ahi, blo, acc0, 0, 0, 0);\
        acc0 = __builtin_amdgcn_mfma_f32_16x16x32_bf16(alo, bhi, acc0, 0, 0, 0);\
      }                                                                        \
    } }

__global__ __launch_bounds__(NTHR, 2) void lstm_main(
        const float* __restrict__ x, const float* __restrict__ Wi2h,
        const float* __restrict__ bi2h, const float* __restrict__ Wh2o,
        const float* __restrict__ bh2o, float* __restrict__ out,
        char* __restrict__ ws) {
    extern __shared__ char lds[];
    const int tid = threadIdx.x, wg = blockIdx.x;
    const int w = tid >> 6, lane = tid & 63, g = lane >> 4, nl = lane & 15;
    const int mt = w & 3, kh = w >> 2;   // wave: batch-tile mt, K-half kh

    // ---- phase 0: build this WG's W frags (cols = gate*1024 + wg*4 + j) ----
    for (int u = tid; u < 3072; u += NTHR) {
        int ak = u >> 4, cl = u & 15;
        int n = (cl >> 2) * 1024 + wg * 4 + (cl & 3);
        bf16x8 hi8, lo8;
#pragma unroll
        for (int j = 0; j < 8; ++j) {
            float v = Wi2h[(size_t)(ak * 8 + j) * 4096 + n];
            __bf16 h = (__bf16)v;
            hi8[j] = h;
            lo8[j] = (__bf16)(v - (float)h);
        }
        *(bf16x8*)(lds + L_WHI + (size_t)u * 16) = hi8;
        *(bf16x8*)(lds + L_WLO + (size_t)u * 16) = lo8;
    }
    const float bias_nl = bi2h[(nl >> 2) * 1024 + wg * 4 + (nl & 3)];
    __syncthreads();

    // ---- XCD discovery + slot registration (exactly 32 WGs per XCD) ----
    unsigned xcc;
    asm("s_getreg_b32 %0, hwreg(HW_REG_XCC_ID)" : "=s"(xcc));
    if (tid == 0) {
        unsigned sl = __hip_atomic_fetch_add((unsigned*)(ws + WS_XCDC) + xcc * 16,
                                             1u, __ATOMIC_RELAXED,
                                             __HIP_MEMORY_SCOPE_AGENT);
        *(unsigned*)(lds + L_EXCH) = sl;
    }
    __syncthreads();
    const unsigned slot = *(volatile unsigned*)(lds + L_EXCH);
    __syncthreads();

    unsigned* flags = (unsigned*)(ws + WS_FLAGS);
    unsigned* my_mb = (unsigned*)(ws + WS_GOMB) + wg * 16;
    float* exch  = (float*)(lds + L_EXCH);
    float* exch2 = (float*)(lds + L_EXCH2);
    float creg = 0.f;

#pragma unroll 1
    for (int t = 0; t < 512; ++t) {
        const char* hb_rd = ws + WS_HBUF + (size_t)(t & 1) * HB_STRIDE;
        char*       hb_wr = ws + WS_HBUF + (size_t)((t + 1) & 1) * HB_STRIDE;
        char* sbuf = ws + WS_STAGE + ((size_t)xcc * 2 + (t & 1)) * STG_STRIDE;
        f32x4 acc0 = {0.f, 0.f, 0.f, 0.f}, acc1 = {0.f, 0.f, 0.f, 0.f};
        const float* xb = x + ((size_t)(mt * 16 + nl) * 512 + t) * 512 + g * 8;

        X_HALF(0)                              // x ksteps 0-3 (hides mailbox lag)

        // ---- wait: all WGs finished step t-1 (h_{t-1} visible at MALL) ----
        if (tid == 0) {
            while (__hip_atomic_load(my_mb, __ATOMIC_RELAXED,
                                     __HIP_MEMORY_SCOPE_AGENT) < (unsigned)t) {}
        }
        __syncthreads();

        // ---- stage my 8KB slice of the h-image into this XCD's L2 ----
        {
            uint32_t soff = slot * 8192 + (uint32_t)tid * 16;
            const char* sin = hb_rd + soff;
            union { u64 q[2]; float4 v; } sv;
            sv.q[0] = __hip_atomic_load((const u64*)sin, __ATOMIC_RELAXED,
                                        __HIP_MEMORY_SCOPE_AGENT);
            sv.q[1] = __hip_atomic_load((const u64*)(sin + 8), __ATOMIC_RELAXED,
                                        __HIP_MEMORY_SCOPE_AGENT);
            *(float4*)(sbuf + soff) = sv.v;    // plain store -> local L2
        }
        __syncthreads();                       // drains vmcnt: slice in L2
        if (tid == 0) {
            unsigned c = __hip_atomic_fetch_add((unsigned*)(ws + WS_SCNT) + xcc * 16,
                                                1u, __ATOMIC_RELAXED,
                                                __HIP_MEMORY_SCOPE_AGENT);
            if (c == 32u * (unsigned)(t + 1) - 1u)   // last stager on this XCD
                __hip_atomic_store((unsigned*)(ws + WS_SFLAG) + xcc * 16,
                                   (unsigned)(t + 1), __ATOMIC_RELAXED,
                                   __HIP_MEMORY_SCOPE_AGENT);
        }

        X_HALF(4)                              // x ksteps 4-7 (hides stage flag)

        // ---- wait: all 32 slices of this XCD staged ----
        if (tid == 0) {
            const unsigned* sf = (const unsigned*)(ws + WS_SFLAG) + xcc * 16;
            while (__hip_atomic_load(sf, __ATOMIC_RELAXED,
                                     __HIP_MEMORY_SCOPE_AGENT) < (unsigned)(t + 1)) {}
        }
        __syncthreads();                       // also: clean vmcnt slate

        // ---- h-part: 16 ksteps from local L2, counted-vmcnt pipeline ----
        {
            const char* sb = sbuf;
            const uint32_t habase = ((uint32_t)(mt * 32 + kh * 16) * 64 + lane) * 16;
            float4 vh[16], vl[16];
            ISSUE(0)
            ISSUE(1)
            WAITV(8);
            COMPB(0)
            ISSUE(2)
            WAITV(8);
            COMPB(1)
            ISSUE(3)
            WAITV(8);
            COMPB(2)
            WAITV(0);
            COMPB(3)
        }

        // ---- epilogue: K-half reduce, activations, cell update ----
        if (kh == 1) {
#pragma unroll
            for (int j = 0; j < 4; ++j)
                exch[mt * 256 + (g * 4 + j) * 16 + nl] = acc0[j] + acc1[j];
        }
        __syncthreads();
        if (kh == 0) {
#pragma unroll
            for (int j = 0; j < 4; ++j) {
                float pre = acc0[j] + acc1[j] + exch[mt * 256 + (g * 4 + j) * 16 + nl]
                          + bias_nl;
                float act = ((nl >> 2) == 2) ? tanh_f(pre) : sigm(pre);
                exch2[mt * 256 + (g * 4 + j) * 16 + nl] = act;
            }
        }
        __syncthreads();
        if (tid < 256) {
            int mt2 = tid >> 6, r = (tid >> 2) & 15, hc = tid & 3;
            const float* a2 = exch2 + mt2 * 256 + r * 16;
            float iv = a2[hc], fv = a2[4 + hc], gv = a2[8 + hc], ov = a2[12 + hc];
            float cc = fv * creg + iv * gv;
            creg = cc;
            float hv = ov * tanh_f(cc);
            __bf16 hh = (__bf16)hv;
            __bf16 hl = (__bf16)(hv - (float)hh);
            int k = 512 + wg * 4 + hc;
            int hs = (k >> 5) - 16, kg = (k >> 3) & 3, j8 = k & 7;
            uint32_t ad = ((uint32_t)(mt2 * 32 + hs) * 64 + kg * 16 + r) * 16 + j8 * 2;
            __hip_atomic_store((unsigned short*)(hb_wr + ad),
                               __builtin_bit_cast(unsigned short, hh),
                               __ATOMIC_RELAXED, __HIP_MEMORY_SCOPE_AGENT);
            __hip_atomic_store((unsigned short*)(hb_wr + HB_LO + ad),
                               __builtin_bit_cast(unsigned short, hl),
                               __ATOMIC_RELAXED, __HIP_MEMORY_SCOPE_AGENT);
            if (t == 511)
                __hip_atomic_store((float*)(ws + WS_HLAST)
                                       + (mt2 * 16 + r) * 1024 + wg * 4 + hc, hv,
                                   __ATOMIC_RELAXED, __HIP_MEMORY_SCOPE_AGENT);
        }
        __syncthreads();   // drains vmcnt -> h stores visible at MALL
        if (tid == 0)
            __hip_atomic_store(&flags[wg], (unsigned)(t + 1),
                               __ATOMIC_RELAXED, __HIP_MEMORY_SCOPE_AGENT);
        // ---- aggregator: wg0 wave0 scans flags, fans out to mailboxes ----
        if (wg == 0 && w == 0) {
            unsigned tgt = (unsigned)(t + 1);
            const u64* f64 = (const u64*)flags;
            for (;;) {
                u64 a = __hip_atomic_load(f64 + 2 * lane,
                          __ATOMIC_RELAXED, __HIP_MEMORY_SCOPE_AGENT);
                u64 b = __hip_atomic_load(f64 + 2 * lane + 1,
                          __ATOMIC_RELAXED, __HIP_MEMORY_SCOPE_AGENT);
                unsigned m0 = min(min((unsigned)a, (unsigned)(a >> 32)),
                                  min((unsigned)b, (unsigned)(b >> 32)));
                if (__all(m0 >= tgt)) break;
            }
            unsigned* mb = (unsigned*)(ws + WS_GOMB);
#pragma unroll
            for (int q = 0; q < 4; ++q)
                __hip_atomic_store(mb + (q * 64 + lane) * 16, tgt,
                                   __ATOMIC_RELAXED, __HIP_MEMORY_SCOPE_AGENT);
        }
    }

    // ---- final projection: out = h_last @ W_h2o + b_h2o ----
    if (tid == 0) {
        while (__hip_atomic_load(my_mb, __ATOMIC_RELAXED,
                                 __HIP_MEMORY_SCOPE_AGENT) < 512u) {}
    }
    __syncthreads();
    __builtin_amdgcn_fence(__ATOMIC_ACQUIRE, "agent");   // once, outside hot loop

    const float* HL = (const float*)(ws + WS_HLAST);
    float* hl = (float*)lds;
    float* pp = (float*)(lds + 8192);
    int bb = wg & 63, q = wg >> 6;
    hl[tid]       = HL[bb * 1024 + tid];
    hl[tid + 512] = HL[bb * 1024 + 512 + tid];
    __syncthreads();
    int c = q * 128 + (tid & 127), kq = tid >> 7;
    const float* wc = Wh2o + c;
    float part = 0.f;
#pragma unroll 8
    for (int k = kq * 256; k < kq * 256 + 256; ++k)
        part += hl[k] * wc[(size_t)k * 512];
    pp[kq * 128 + (tid & 127)] = part;
    __syncthreads();
    if (tid < 128)
        out[bb * 512 + q * 128 + tid] =
            pp[tid] + pp[128 + tid] + pp[256 + tid] + pp[384 + tid] + bh2o[q * 128 + tid];
}

extern "C" void kernel_launch(void* const* d_in, const int* in_sizes, int n_in,
                              void* d_out, int out_size, void* d_ws, size_t ws_size,
                              hipStream_t stream) {
    const float* x    = (const float*)d_in[0];
    const float* Wi2h = (const float*)d_in[1];
    const float* bi2h = (const float*)d_in[2];
    const float* Wh2o = (const float*)d_in[3];
    const float* bh2o = (const float*)d_in[4];
    float* out = (float*)d_out;
    char* ws = (char*)d_ws;

    hipFuncSetAttribute(reinterpret_cast<const void*>(lstm_main),
                        hipFuncAttributeMaxDynamicSharedMemorySize, LDS_BYTES);

    lstm_init<<<256, 256, 0, stream>>>(ws);

    void* args[] = {(void*)&x, (void*)&Wi2h, (void*)&bi2h, (void*)&Wh2o,
                    (void*)&bh2o, (void*)&out, (void*)&ws};
    hipLaunchCooperativeKernel(reinterpret_cast<void*>(lstm_main),
                               dim3(NWG), dim3(NTHR), args, LDS_BYTES, stream);
}